// Round 4
// baseline (672.933 us; speedup 1.0000x reference)
//
#include <hip/hip_runtime.h>
#include <hip/hip_bf16.h>

#define H 128           // H_IN == H_OUT == 128
#define BW 128          // nodes per coarse bucket
#define BSH 7           // log2(BW)

typedef __attribute__((ext_vector_type(8))) short short8;
typedef __attribute__((ext_vector_type(4))) float f32x4;

__device__ inline unsigned short f2bf(float f) {
    union { float f; unsigned int u; } v; v.f = f;
    unsigned int r = (v.u + 0x7fffu + ((v.u >> 16) & 1u)) >> 16;
    return (unsigned short)r;
}
__device__ inline float bf2f(unsigned short h) {
    union { unsigned int u; float f; } v; v.u = ((unsigned int)h) << 16;
    return v.f;
}

// ---------------------------------------------------------------------------
// Phase A: coarse histogram of dst>>BSH via per-block LDS histograms
__global__ __launch_bounds__(256) void chist_kernel(const int* __restrict__ ei,
                                                    int* __restrict__ chist, int E) {
    __shared__ int h[1024];
    for (int i = threadIdx.x; i < 1024; i += 256) h[i] = 0;
    __syncthreads();
    for (int e = blockIdx.x * 256 + threadIdx.x; e < E; e += gridDim.x * 256)
        atomicAdd(&h[ei[E + e] >> BSH], 1);
    __syncthreads();
    for (int i = threadIdx.x; i < 1024; i += 256) {
        int v = h[i];
        if (v) atomicAdd(&chist[i], v);
    }
}

// Phase B: exclusive scan of nb (<=1024) bucket counts -> cstart, init ccur
__global__ __launch_bounds__(1024) void cscan_kernel(const int* __restrict__ chist,
                                                     int* __restrict__ cstart,
                                                     int* __restrict__ ccur,
                                                     int nb, int E) {
    __shared__ int s[1024];
    int t = threadIdx.x;
    int v = (t < nb) ? chist[t] : 0;
    s[t] = v;
    __syncthreads();
    for (int off = 1; off < 1024; off <<= 1) {
        int add = (t >= off) ? s[t - off] : 0;
        __syncthreads();
        s[t] += add;
        __syncthreads();
    }
    if (t < nb) {
        int excl = s[t] - v;
        cstart[t] = excl;
        ccur[t] = excl;
    }
    if (t == 0) cstart[nb] = E;
}

// Phase C: scatter (src,dst) into coarse bucket regions (dense appends)
__global__ __launch_bounds__(256) void cscatter_kernel(const int* __restrict__ ei,
                                                       int* __restrict__ ccur,
                                                       int2* __restrict__ tmp, int E) {
    int e = blockIdx.x * 256 + threadIdx.x;
    if (e >= E) return;
    int s = ei[e], d = ei[E + e];
    int slot = atomicAdd(&ccur[d >> BSH], 1);
    tmp[slot] = make_int2(s, d);
}

// Phase D: per bucket: local histogram (=deg) + dinv, local scan, place srcs.
// entries written contiguously per bucket; cursor[n] = row END, deg[n] = count.
__global__ __launch_bounds__(256) void csr_kernel(const int2* __restrict__ tmp,
                                                  const int* __restrict__ cstart,
                                                  int* __restrict__ entries,
                                                  int* __restrict__ cursor,
                                                  int* __restrict__ deg,
                                                  float* __restrict__ dinv, int N) {
    __shared__ int ldeg[BW];
    __shared__ int lscan[BW];
    __shared__ int lcur[BW];
    const int b = blockIdx.x;
    const int nstart = b << BSH;
    const int estart = cstart[b];
    const int eend = cstart[b + 1];
    const int t = threadIdx.x;

    if (t < BW) ldeg[t] = 0;
    __syncthreads();
    for (int i = estart + t; i < eend; i += 256)
        atomicAdd(&ldeg[tmp[i].y - nstart], 1);
    __syncthreads();
    if (t == 0) {
        int acc = 0;
        for (int j = 0; j < BW; ++j) { lscan[j] = acc; acc += ldeg[j]; }
    }
    __syncthreads();
    if (t < BW && nstart + t < N) {
        int dg = ldeg[t];
        deg[nstart + t] = dg;
        dinv[nstart + t] = rsqrtf((float)dg + 2.0f);
        cursor[nstart + t] = estart + lscan[t] + dg;   // row end
        lcur[t] = lscan[t];
    }
    __syncthreads();
    for (int i = estart + t; i < eend; i += 256) {
        int2 ed = tmp[i];
        int sl = atomicAdd(&lcur[ed.y - nstart], 1);
        entries[estart + sl] = ed.x;
    }
}

// ---------------------------------------------------------------------------
// cast x (fp32) -> xh (bf16), 8 elems/thread
__global__ __launch_bounds__(256) void cast_kernel(const float* __restrict__ x,
                                                   unsigned short* __restrict__ xh,
                                                   int total8) {
    int i = blockIdx.x * 256 + threadIdx.x;
    if (i >= total8) return;
    const float4* xp = (const float4*)x;
    float4 a = xp[2 * i], b = xp[2 * i + 1];
    short8 v;
    v[0] = (short)f2bf(a.x); v[1] = (short)f2bf(a.y);
    v[2] = (short)f2bf(a.z); v[3] = (short)f2bf(a.w);
    v[4] = (short)f2bf(b.x); v[5] = (short)f2bf(b.y);
    v[6] = (short)f2bf(b.z); v[7] = (short)f2bf(b.w);
    ((short8*)xh)[i] = v;
}

// ---------------------------------------------------------------------------
// Pack W matrices into MFMA B-fragment layout (bf16), 3 planes:
//   mat 0: Wc_hi   mat 1: Ws_hi   mat 2: Ws_lo
__global__ __launch_bounds__(256) void wpack_kernel(const float* __restrict__ Wc,
                                                    const float* __restrict__ Ws,
                                                    short8* __restrict__ wp) {
    int t = blockIdx.x * 256 + threadIdx.x;   // 0..2047
    if (t >= 2048) return;
    int lane = t & 63;
    int nt = (t >> 6) & 7;
    int ks = t >> 9;
    int kbase = ks * 32 + (lane >> 4) * 8;
    int col = nt * 16 + (lane & 15);
    short8 whc, whs, wls;
    #pragma unroll
    for (int j = 0; j < 8; ++j) {
        float wc = Wc[(kbase + j) * H + col];
        float ws = Ws[(kbase + j) * H + col];
        unsigned short hc = f2bf(wc);
        unsigned short hs = f2bf(ws);
        whc[j] = (short)hc;
        whs[j] = (short)hs;
        wls[j] = (short)f2bf(ws - bf2f(hs));
    }
    int base = (ks * 8 + nt) * 64 + lane;
    wp[base] = whc;
    wp[2048 + base] = whs;
    wp[4096 + base] = wls;
}

// ---------------------------------------------------------------------------
// Gather aggregation on bf16 x: z = sum(norm * x[src]) + 2*d^2*x[node], bf16.
__global__ __launch_bounds__(256) void agg_kernel(const int* __restrict__ entries,
                                                  const int* __restrict__ cursor,
                                                  const int* __restrict__ deg,
                                                  const float* __restrict__ dinv,
                                                  const unsigned short* __restrict__ xh,
                                                  unsigned short* __restrict__ z, int N) {
    int node = blockIdx.x * 4 + (threadIdx.x >> 6);
    if (node >= N) return;
    int lane = threadIdx.x & 63;
    int end = cursor[node];
    int start = end - deg[node];
    float dd = dinv[node];
    const uint* x2 = (const uint*)xh;
    float accx = 0.f, accy = 0.f;

    for (int c = start; c < end; c += 64) {
        int rem = end - c;
        int src = 0;
        float nm = 0.f;
        if (lane < rem) {
            src = entries[c + lane];
            nm = dinv[src] * dd;
        }
        int cnt = rem < 64 ? rem : 64;
        for (int t = 0; t < cnt; ++t) {
            int ss = __shfl(src, t);
            float w = __shfl(nm, t);
            uint hv = x2[ss * 64 + lane];
            accx += w * bf2f((unsigned short)(hv & 0xffffu));
            accy += w * bf2f((unsigned short)(hv >> 16));
        }
    }

    uint sv = x2[node * 64 + lane];
    float sl = 2.f * dd * dd;
    accx += sl * bf2f((unsigned short)(sv & 0xffffu));
    accy += sl * bf2f((unsigned short)(sv >> 16));
    uint outw = (uint)f2bf(accx) | ((uint)f2bf(accy) << 16);
    ((uint*)z)[node * 64 + lane] = outw;
}

// ---------------------------------------------------------------------------
// MFMA GEMM: out = ELU( z@Wc + x@Ws + bc + bsk ), split-bf16 on the x path.
__global__ __launch_bounds__(256) void gemm_kernel(const unsigned short* __restrict__ zb,
                                                   const float* __restrict__ x,
                                                   const short8* __restrict__ wp,
                                                   const float* __restrict__ bc,
                                                   const float* __restrict__ bsk,
                                                   float* __restrict__ out, int N) {
    const int lane = threadIdx.x & 63;
    const int wave = threadIdx.x >> 6;
    const int m = lane & 15;
    const int quad = lane >> 4;
    const int row = blockIdx.x * 64 + wave * 16 + m;
    const bool rowok = row < N;

    f32x4 acc[8];
    #pragma unroll
    for (int i = 0; i < 8; ++i) acc[i] = (f32x4){0.f, 0.f, 0.f, 0.f};

    #pragma unroll
    for (int ks = 0; ks < 4; ++ks) {
        const int k0 = ks * 32 + quad * 8;
        short8 za = {0, 0, 0, 0, 0, 0, 0, 0};
        short8 xa_h = {0, 0, 0, 0, 0, 0, 0, 0};
        short8 xa_l = {0, 0, 0, 0, 0, 0, 0, 0};
        if (rowok) {
            za = ((const short8*)zb)[(row * H + k0) >> 3];
            float4 a = *(const float4*)&x[row * H + k0];
            float4 b = *(const float4*)&x[row * H + k0 + 4];
            float xv[8] = {a.x, a.y, a.z, a.w, b.x, b.y, b.z, b.w};
            #pragma unroll
            for (int j = 0; j < 8; ++j) {
                unsigned short h = f2bf(xv[j]);
                xa_h[j] = (short)h;
                xa_l[j] = (short)f2bf(xv[j] - bf2f(h));
            }
        }
        #pragma unroll
        for (int nt = 0; nt < 8; ++nt) {
            int base = (ks * 8 + nt) * 64 + lane;
            short8 bch = wp[base];
            short8 bsh = wp[2048 + base];
            short8 bsl = wp[4096 + base];
            acc[nt] = __builtin_amdgcn_mfma_f32_16x16x32_bf16(za, bch, acc[nt], 0, 0, 0);
            acc[nt] = __builtin_amdgcn_mfma_f32_16x16x32_bf16(xa_h, bsh, acc[nt], 0, 0, 0);
            acc[nt] = __builtin_amdgcn_mfma_f32_16x16x32_bf16(xa_l, bsh, acc[nt], 0, 0, 0);
            acc[nt] = __builtin_amdgcn_mfma_f32_16x16x32_bf16(xa_h, bsl, acc[nt], 0, 0, 0);
        }
    }

    const int orow_base = blockIdx.x * 64 + wave * 16 + quad * 4;
    #pragma unroll
    for (int nt = 0; nt < 8; ++nt) {
        int col = nt * 16 + m;
        float bias = bc[col] + bsk[col];
        #pragma unroll
        for (int r = 0; r < 4; ++r) {
            int orow = orow_base + r;
            if (orow < N) {
                float v = acc[nt][r] + bias;
                v = v > 0.f ? v : 0.1f * (__expf(v) - 1.f);
                out[orow * H + col] = v;
            }
        }
    }
}

// ---------------------------------------------------------------------------
extern "C" void kernel_launch(void* const* d_in, const int* in_sizes, int n_in,
                              void* d_out, int out_size, void* d_ws, size_t ws_size,
                              hipStream_t stream) {
    const float* x   = (const float*)d_in[0];
    const int*   ei  = (const int*)d_in[1];
    const float* Wc  = (const float*)d_in[2];
    const float* bc  = (const float*)d_in[3];
    const float* Wsk = (const float*)d_in[4];
    const float* bsk = (const float*)d_in[5];
    float* out = (float*)d_out;

    const int N = in_sizes[0] / H;     // 100000
    const int E = in_sizes[1] / 2;     // 1600000
    const int nb = (N + BW - 1) / BW;  // 782 coarse buckets (<=1024)

    // workspace layout (byte offsets):
    //   0        cstart (nb+1 ints)
    //   16K      chist/ccur (nb ints)
    //   512K     cursor (N ints, row ends)
    //   1M       deg (N ints)
    //   1.5M     dinv (N floats)
    //   2M       wp (3*2048 short8 = 96KB)
    //   2.5M     entries (E ints, 6.4MB)            -> ends ~9.02MB
    //   9.25MB   tmp (E int2, 12.8MB)  [dead after csr_kernel]
    //   9.25MB   z (bf16 N*H, 25.6MB)  [overlays tmp; written by agg]
    //   34MiB    xh (bf16 N*H, 25.6MB)               -> ends ~58.4MiB
    char* w = (char*)d_ws;
    int*            cstart  = (int*)w;
    int*            ccur    = (int*)(w + 16384);
    int*            cursor  = (int*)(w + 524288);
    int*            deg     = (int*)(w + 1048576);
    float*          dinv    = (float*)(w + 1572864);
    short8*         wp      = (short8*)(w + 2097152);
    int*            entries = (int*)(w + 2621440);
    int2*           tmp     = (int2*)(w + 9699328);
    unsigned short* z       = (unsigned short*)(w + 9699328);
    unsigned short* xh      = (unsigned short*)(w + 35651584);

    hipMemsetAsync(ccur, 0, 4096, stream);   // chist zero-init

    chist_kernel<<<512, 256, 0, stream>>>(ei, ccur, E);
    cscan_kernel<<<1, 1024, 0, stream>>>(ccur, cstart, ccur, nb, E);
    cscatter_kernel<<<(E + 255) / 256, 256, 0, stream>>>(ei, ccur, tmp, E);
    csr_kernel<<<nb, 256, 0, stream>>>(tmp, cstart, entries, cursor, deg, dinv, N);

    cast_kernel<<<(N * H / 8 + 255) / 256, 256, 0, stream>>>(x, xh, N * H / 8);
    wpack_kernel<<<8, 256, 0, stream>>>(Wc, Wsk, wp);

    // z = sum(norm * x[src]) + selfloop (bf16)  [z overlays tmp - tmp is dead]
    agg_kernel<<<(N + 3) / 4, 256, 0, stream>>>(entries, cursor, deg, dinv, xh, z, N);

    // out = ELU(z@Wc + x@Ws + biases)
    gemm_kernel<<<(N + 63) / 64, 256, 0, stream>>>(z, x, wp, bc, bsk, out, N);
}

// Round 5
// 319.789 us; speedup vs baseline: 2.1043x; 2.1043x over previous
//
#include <hip/hip_runtime.h>
#include <hip/hip_bf16.h>

#define H 128           // H_IN == H_OUT == 128
#define BW 128          // nodes per coarse bucket
#define BSH 7           // log2(BW)
#define NB 256          // partition blocks for counting sort

typedef __attribute__((ext_vector_type(8))) short short8;
typedef __attribute__((ext_vector_type(4))) float f32x4;

__device__ inline unsigned short f2bf(float f) {
    union { float f; unsigned int u; } v; v.f = f;
    unsigned int r = (v.u + 0x7fffu + ((v.u >> 16) & 1u)) >> 16;
    return (unsigned short)r;
}
__device__ inline float bf2f(unsigned short h) {
    union { unsigned int u; float f; } v; v.u = ((unsigned int)h) << 16;
    return v.f;
}

// ---------------------------------------------------------------------------
// P1: per-block LDS histogram of dst>>BSH over this block's edge chunk
__global__ __launch_bounds__(256) void p1_hist(const int* __restrict__ ei,
                                               int* __restrict__ counts,
                                               int E, int nbu, int chunk) {
    __shared__ int h[1024];
    for (int i = threadIdx.x; i < nbu; i += 256) h[i] = 0;
    __syncthreads();
    const int b = blockIdx.x;
    const int lo = b * chunk;
    const int hi = min(E, lo + chunk);
    for (int e = lo + threadIdx.x; e < hi; e += 256)
        atomicAdd(&h[ei[E + e] >> BSH], 1);
    __syncthreads();
    for (int i = threadIdx.x; i < nbu; i += 256) counts[b * nbu + i] = h[i];
}

// P2: per bucket, exclusive scan of its NB block-counts
__global__ __launch_bounds__(NB) void p2_scan(const int* __restrict__ counts,
                                              int* __restrict__ scanned,
                                              int* __restrict__ btot, int nbu) {
    __shared__ int s[NB];
    const int k = blockIdx.x, t = threadIdx.x;
    int v = counts[t * nbu + k];
    s[t] = v;
    __syncthreads();
    for (int off = 1; off < NB; off <<= 1) {
        int a = (t >= off) ? s[t - off] : 0;
        __syncthreads();
        s[t] += a;
        __syncthreads();
    }
    scanned[t * nbu + k] = s[t] - v;
    if (t == NB - 1) btot[k] = s[t];
}

// P3: exclusive scan of bucket totals -> cstart
__global__ __launch_bounds__(1024) void p3_scan(const int* __restrict__ btot,
                                                int* __restrict__ cstart,
                                                int nbu, int E) {
    __shared__ int s[1024];
    const int t = threadIdx.x;
    int v = (t < nbu) ? btot[t] : 0;
    s[t] = v;
    __syncthreads();
    for (int off = 1; off < 1024; off <<= 1) {
        int a = (t >= off) ? s[t - off] : 0;
        __syncthreads();
        s[t] += a;
        __syncthreads();
    }
    if (t < nbu) cstart[t] = s[t] - v;
    if (t == 0) cstart[nbu] = E;
}

// P5: scatter packed edges into exact slots (no global atomics)
__global__ __launch_bounds__(256) void p5_scatter(const int* __restrict__ ei,
                                                  const int* __restrict__ cstart,
                                                  const int* __restrict__ scanned,
                                                  int* __restrict__ tmp,
                                                  int E, int nbu, int chunk) {
    __shared__ int lbase[1024];
    const int b = blockIdx.x;
    for (int k = threadIdx.x; k < nbu; k += 256)
        lbase[k] = cstart[k] + scanned[b * nbu + k];
    __syncthreads();
    const int lo = b * chunk;
    const int hi = min(E, lo + chunk);
    for (int e = lo + threadIdx.x; e < hi; e += 256) {
        int s = ei[e], d = ei[E + e];
        int slot = atomicAdd(&lbase[d >> BSH], 1);
        tmp[slot] = ((d & (BW - 1)) << 17) | s;
    }
}

// Phase D: per bucket, local histogram+scan -> rstart, dinv, sorted entries
__global__ __launch_bounds__(256) void csr_kernel(const int* __restrict__ tmp,
                                                  const int* __restrict__ cstart,
                                                  int* __restrict__ entries,
                                                  int* __restrict__ rstart,
                                                  float* __restrict__ dinv,
                                                  int N, int E) {
    __shared__ int ldeg[BW];
    __shared__ int lscan[BW];
    __shared__ int lcur[BW];
    const int b = blockIdx.x;
    const int nstart = b << BSH;
    const int estart = cstart[b];
    const int eend = cstart[b + 1];
    const int t = threadIdx.x;

    if (t < BW) ldeg[t] = 0;
    __syncthreads();
    for (int i = estart + t; i < eend; i += 256)
        atomicAdd(&ldeg[(tmp[i] >> 17) & (BW - 1)], 1);
    __syncthreads();
    if (t == 0) {
        int acc = 0;
        for (int j = 0; j < BW; ++j) { lscan[j] = acc; acc += ldeg[j]; }
    }
    __syncthreads();
    if (t < BW) {
        lcur[t] = lscan[t];
        int n = nstart + t;
        if (n < N) {
            rstart[n] = estart + lscan[t];
            dinv[n] = rsqrtf((float)ldeg[t] + 2.0f);
        }
    }
    __syncthreads();
    for (int i = estart + t; i < eend; i += 256) {
        int v = tmp[i];
        int sl = atomicAdd(&lcur[(v >> 17) & (BW - 1)], 1);
        entries[estart + sl] = v & 0x1FFFF;
    }
    if (b == 0 && t == 0) rstart[N] = E;
}

// ---------------------------------------------------------------------------
// cast x (fp32) -> xh (bf16), 8 elems/thread
__global__ __launch_bounds__(256) void cast_kernel(const float* __restrict__ x,
                                                   unsigned short* __restrict__ xh,
                                                   int total8) {
    int i = blockIdx.x * 256 + threadIdx.x;
    if (i >= total8) return;
    const float4* xp = (const float4*)x;
    float4 a = xp[2 * i], b = xp[2 * i + 1];
    short8 v;
    v[0] = (short)f2bf(a.x); v[1] = (short)f2bf(a.y);
    v[2] = (short)f2bf(a.z); v[3] = (short)f2bf(a.w);
    v[4] = (short)f2bf(b.x); v[5] = (short)f2bf(b.y);
    v[6] = (short)f2bf(b.z); v[7] = (short)f2bf(b.w);
    ((short8*)xh)[i] = v;
}

// ---------------------------------------------------------------------------
// Pack W matrices into MFMA B-fragment layout (bf16), 3 planes:
//   mat 0: Wc_hi   mat 1: Ws_hi   mat 2: Ws_lo
__global__ __launch_bounds__(256) void wpack_kernel(const float* __restrict__ Wc,
                                                    const float* __restrict__ Ws,
                                                    short8* __restrict__ wp) {
    int t = blockIdx.x * 256 + threadIdx.x;   // 0..2047
    if (t >= 2048) return;
    int lane = t & 63;
    int nt = (t >> 6) & 7;
    int ks = t >> 9;
    int kbase = ks * 32 + (lane >> 4) * 8;
    int col = nt * 16 + (lane & 15);
    short8 whc, whs, wls;
    #pragma unroll
    for (int j = 0; j < 8; ++j) {
        float wc = Wc[(kbase + j) * H + col];
        float ws = Ws[(kbase + j) * H + col];
        unsigned short hc = f2bf(wc);
        unsigned short hs = f2bf(ws);
        whc[j] = (short)hc;
        whs[j] = (short)hs;
        wls[j] = (short)f2bf(ws - bf2f(hs));
    }
    int base = (ks * 8 + nt) * 64 + lane;
    wp[base] = whc;
    wp[2048 + base] = whs;
    wp[4096 + base] = wls;
}

// ---------------------------------------------------------------------------
// Gather aggregation on bf16 x: z = sum(norm * x[src]) + 2*d^2*x[node], bf16.
__global__ __launch_bounds__(256) void agg_kernel(const int* __restrict__ entries,
                                                  const int* __restrict__ rstart,
                                                  const float* __restrict__ dinv,
                                                  const unsigned short* __restrict__ xh,
                                                  unsigned short* __restrict__ z, int N) {
    int node = blockIdx.x * 4 + (threadIdx.x >> 6);
    if (node >= N) return;
    int lane = threadIdx.x & 63;
    int start = rstart[node];
    int end = rstart[node + 1];
    float dd = dinv[node];
    const uint* x2 = (const uint*)xh;
    float accx = 0.f, accy = 0.f;

    for (int c = start; c < end; c += 64) {
        int rem = end - c;
        int src = 0;
        float nm = 0.f;
        if (lane < rem) {
            src = entries[c + lane];
            nm = dinv[src] * dd;
        }
        int cnt = rem < 64 ? rem : 64;
        for (int t = 0; t < cnt; ++t) {
            int ss = __shfl(src, t);
            float w = __shfl(nm, t);
            uint hv = x2[ss * 64 + lane];
            accx += w * bf2f((unsigned short)(hv & 0xffffu));
            accy += w * bf2f((unsigned short)(hv >> 16));
        }
    }

    uint sv = x2[node * 64 + lane];
    float sl = 2.f * dd * dd;
    accx += sl * bf2f((unsigned short)(sv & 0xffffu));
    accy += sl * bf2f((unsigned short)(sv >> 16));
    uint outw = (uint)f2bf(accx) | ((uint)f2bf(accy) << 16);
    ((uint*)z)[node * 64 + lane] = outw;
}

// ---------------------------------------------------------------------------
// MFMA GEMM: out = ELU( z@Wc + x@Ws + bc + bsk ), split-bf16 on the x path.
__global__ __launch_bounds__(256) void gemm_kernel(const unsigned short* __restrict__ zb,
                                                   const float* __restrict__ x,
                                                   const short8* __restrict__ wp,
                                                   const float* __restrict__ bc,
                                                   const float* __restrict__ bsk,
                                                   float* __restrict__ out, int N) {
    const int lane = threadIdx.x & 63;
    const int wave = threadIdx.x >> 6;
    const int m = lane & 15;
    const int quad = lane >> 4;
    const int row = blockIdx.x * 64 + wave * 16 + m;
    const bool rowok = row < N;

    f32x4 acc[8];
    #pragma unroll
    for (int i = 0; i < 8; ++i) acc[i] = (f32x4){0.f, 0.f, 0.f, 0.f};

    #pragma unroll
    for (int ks = 0; ks < 4; ++ks) {
        const int k0 = ks * 32 + quad * 8;
        short8 za = {0, 0, 0, 0, 0, 0, 0, 0};
        short8 xa_h = {0, 0, 0, 0, 0, 0, 0, 0};
        short8 xa_l = {0, 0, 0, 0, 0, 0, 0, 0};
        if (rowok) {
            za = ((const short8*)zb)[(row * H + k0) >> 3];
            float4 a = *(const float4*)&x[row * H + k0];
            float4 b = *(const float4*)&x[row * H + k0 + 4];
            float xv[8] = {a.x, a.y, a.z, a.w, b.x, b.y, b.z, b.w};
            #pragma unroll
            for (int j = 0; j < 8; ++j) {
                unsigned short h = f2bf(xv[j]);
                xa_h[j] = (short)h;
                xa_l[j] = (short)f2bf(xv[j] - bf2f(h));
            }
        }
        #pragma unroll
        for (int nt = 0; nt < 8; ++nt) {
            int base = (ks * 8 + nt) * 64 + lane;
            short8 bch = wp[base];
            short8 bsh = wp[2048 + base];
            short8 bsl = wp[4096 + base];
            acc[nt] = __builtin_amdgcn_mfma_f32_16x16x32_bf16(za, bch, acc[nt], 0, 0, 0);
            acc[nt] = __builtin_amdgcn_mfma_f32_16x16x32_bf16(xa_h, bsh, acc[nt], 0, 0, 0);
            acc[nt] = __builtin_amdgcn_mfma_f32_16x16x32_bf16(xa_l, bsh, acc[nt], 0, 0, 0);
            acc[nt] = __builtin_amdgcn_mfma_f32_16x16x32_bf16(xa_h, bsl, acc[nt], 0, 0, 0);
        }
    }

    const int orow_base = blockIdx.x * 64 + wave * 16 + quad * 4;
    #pragma unroll
    for (int nt = 0; nt < 8; ++nt) {
        int col = nt * 16 + m;
        float bias = bc[col] + bsk[col];
        #pragma unroll
        for (int r = 0; r < 4; ++r) {
            int orow = orow_base + r;
            if (orow < N) {
                float v = acc[nt][r] + bias;
                v = v > 0.f ? v : 0.1f * (__expf(v) - 1.f);
                out[orow * H + col] = v;
            }
        }
    }
}

// ---------------------------------------------------------------------------
extern "C" void kernel_launch(void* const* d_in, const int* in_sizes, int n_in,
                              void* d_out, int out_size, void* d_ws, size_t ws_size,
                              hipStream_t stream) {
    const float* x   = (const float*)d_in[0];
    const int*   ei  = (const int*)d_in[1];
    const float* Wc  = (const float*)d_in[2];
    const float* bc  = (const float*)d_in[3];
    const float* Wsk = (const float*)d_in[4];
    const float* bsk = (const float*)d_in[5];
    float* out = (float*)d_out;

    const int N = in_sizes[0] / H;       // 100000
    const int E = in_sizes[1] / 2;       // 1600000
    const int nbu = (N + BW - 1) / BW;   // 782 coarse buckets (<=1024)
    const int chunk = (E + NB - 1) / NB; // 6250 edges per partition block

    // workspace layout (byte offsets):
    //   0         cstart (nbu+1 ints, ~3.1KB)
    //   8192      btot (nbu ints)
    //   16384     wp (96KB)                       -> ends 114688
    //   131072    rstart (N+1 ints, 400KB)        -> ends 531076
    //   540672    dinv (N floats, 400KB)          -> ends 940672
    //   1048576   counts (NB*nbu ints, ~800KB)    -> ends ~1.85M
    //   1900544   scanned (NB*nbu ints, ~800KB)   -> ends ~2.70M
    //   2752512   entries (E ints, 6.4MB)         -> ends ~9.15M
    //   9216000   tmp (E ints, 6.4MB) [dead after csr]
    //   9216000   z (bf16 N*H, 25.6MB) [overlays tmp] -> ends ~34.8M
    //   34816000  xh (bf16 N*H, 25.6MB)           -> ends ~60.4M
    char* w = (char*)d_ws;
    int*            cstart  = (int*)w;
    int*            btot    = (int*)(w + 8192);
    short8*         wp      = (short8*)(w + 16384);
    int*            rstart  = (int*)(w + 131072);
    float*          dinv    = (float*)(w + 540672);
    int*            counts  = (int*)(w + 1048576);
    int*            scanned = (int*)(w + 1900544);
    int*            entries = (int*)(w + 2752512);
    int*            tmp     = (int*)(w + 9216000);
    unsigned short* z       = (unsigned short*)(w + 9216000);
    unsigned short* xh      = (unsigned short*)(w + 34816000);

    p1_hist<<<NB, 256, 0, stream>>>(ei, counts, E, nbu, chunk);
    p2_scan<<<nbu, NB, 0, stream>>>(counts, scanned, btot, nbu);
    p3_scan<<<1, 1024, 0, stream>>>(btot, cstart, nbu, E);
    p5_scatter<<<NB, 256, 0, stream>>>(ei, cstart, scanned, tmp, E, nbu, chunk);
    csr_kernel<<<nbu, 256, 0, stream>>>(tmp, cstart, entries, rstart, dinv, N, E);

    cast_kernel<<<(N * H / 8 + 255) / 256, 256, 0, stream>>>(x, xh, N * H / 8);
    wpack_kernel<<<8, 256, 0, stream>>>(Wc, Wsk, wp);

    // z = sum(norm * x[src]) + selfloop (bf16)  [z overlays tmp - tmp dead]
    agg_kernel<<<(N + 3) / 4, 256, 0, stream>>>(entries, rstart, dinv, xh, z, N);

    // out = ELU(z@Wc + x@Ws + biases)
    gemm_kernel<<<(N + 63) / 64, 256, 0, stream>>>(z, x, wp, bc, bsk, out, N);
}

// Round 6
// 284.340 us; speedup vs baseline: 2.3667x; 1.1247x over previous
//
#include <hip/hip_runtime.h>
#include <hip/hip_bf16.h>

#define H 128           // H_IN == H_OUT == 128
#define BW 128          // nodes per coarse bucket
#define BSH 7           // log2(BW)
#define NB 256          // partition blocks for counting sort

typedef __attribute__((ext_vector_type(8))) short short8;
typedef __attribute__((ext_vector_type(4))) float f32x4;

__device__ inline unsigned short f2bf(float f) {
    union { float f; unsigned int u; } v; v.f = f;
    unsigned int r = (v.u + 0x7fffu + ((v.u >> 16) & 1u)) >> 16;
    return (unsigned short)r;
}
__device__ inline float bf2f(unsigned short h) {
    union { unsigned int u; float f; } v; v.u = ((unsigned int)h) << 16;
    return v.f;
}

// ---------------------------------------------------------------------------
// P1: per-block LDS histogram of dst>>BSH over this block's edge chunk
__global__ __launch_bounds__(256) void p1_hist(const int* __restrict__ ei,
                                               int* __restrict__ counts,
                                               int E, int nbu, int chunk) {
    __shared__ int h[1024];
    for (int i = threadIdx.x; i < nbu; i += 256) h[i] = 0;
    __syncthreads();
    const int b = blockIdx.x;
    const int lo = b * chunk;
    const int hi = min(E, lo + chunk);
    for (int e = lo + threadIdx.x; e < hi; e += 256)
        atomicAdd(&h[ei[E + e] >> BSH], 1);
    __syncthreads();
    for (int i = threadIdx.x; i < nbu; i += 256) counts[b * nbu + i] = h[i];
}

// P2: per bucket, exclusive scan of its NB block-counts
__global__ __launch_bounds__(NB) void p2_scan(const int* __restrict__ counts,
                                              int* __restrict__ scanned,
                                              int* __restrict__ btot, int nbu) {
    __shared__ int s[NB];
    const int k = blockIdx.x, t = threadIdx.x;
    int v = counts[t * nbu + k];
    s[t] = v;
    __syncthreads();
    for (int off = 1; off < NB; off <<= 1) {
        int a = (t >= off) ? s[t - off] : 0;
        __syncthreads();
        s[t] += a;
        __syncthreads();
    }
    scanned[t * nbu + k] = s[t] - v;
    if (t == NB - 1) btot[k] = s[t];
}

// P3: exclusive scan of bucket totals -> cstart
__global__ __launch_bounds__(1024) void p3_scan(const int* __restrict__ btot,
                                                int* __restrict__ cstart,
                                                int nbu, int E) {
    __shared__ int s[1024];
    const int t = threadIdx.x;
    int v = (t < nbu) ? btot[t] : 0;
    s[t] = v;
    __syncthreads();
    for (int off = 1; off < 1024; off <<= 1) {
        int a = (t >= off) ? s[t - off] : 0;
        __syncthreads();
        s[t] += a;
        __syncthreads();
    }
    if (t < nbu) cstart[t] = s[t] - v;
    if (t == 0) cstart[nbu] = E;
}

// P5: scatter packed edges into exact slots (no global atomics)
__global__ __launch_bounds__(256) void p5_scatter(const int* __restrict__ ei,
                                                  const int* __restrict__ cstart,
                                                  const int* __restrict__ scanned,
                                                  int* __restrict__ tmp,
                                                  int E, int nbu, int chunk) {
    __shared__ int lbase[1024];
    const int b = blockIdx.x;
    for (int k = threadIdx.x; k < nbu; k += 256)
        lbase[k] = cstart[k] + scanned[b * nbu + k];
    __syncthreads();
    const int lo = b * chunk;
    const int hi = min(E, lo + chunk);
    for (int e = lo + threadIdx.x; e < hi; e += 256) {
        int s = ei[e], d = ei[E + e];
        int slot = atomicAdd(&lbase[d >> BSH], 1);
        tmp[slot] = ((d & (BW - 1)) << 17) | s;
    }
}

// Phase D: per bucket, local histogram+scan -> rstart, dinv, ainv, entries
__global__ __launch_bounds__(256) void csr_kernel(const int* __restrict__ tmp,
                                                  const int* __restrict__ cstart,
                                                  const float* __restrict__ invs,
                                                  int* __restrict__ entries,
                                                  int* __restrict__ rstart,
                                                  float* __restrict__ dinv,
                                                  float* __restrict__ ainv,
                                                  int N, int E) {
    __shared__ int ldeg[BW];
    __shared__ int lscan[BW];
    __shared__ int lcur[BW];
    const int b = blockIdx.x;
    const int nstart = b << BSH;
    const int estart = cstart[b];
    const int eend = cstart[b + 1];
    const int t = threadIdx.x;

    if (t < BW) ldeg[t] = 0;
    __syncthreads();
    for (int i = estart + t; i < eend; i += 256)
        atomicAdd(&ldeg[(tmp[i] >> 17) & (BW - 1)], 1);
    __syncthreads();
    if (t == 0) {
        int acc = 0;
        for (int j = 0; j < BW; ++j) { lscan[j] = acc; acc += ldeg[j]; }
    }
    __syncthreads();
    if (t < BW) {
        lcur[t] = lscan[t];
        int n = nstart + t;
        if (n < N) {
            float dv = rsqrtf((float)ldeg[t] + 2.0f);
            rstart[n] = estart + lscan[t];
            dinv[n] = dv;
            ainv[n] = dv * invs[n];
        }
    }
    __syncthreads();
    for (int i = estart + t; i < eend; i += 256) {
        int v = tmp[i];
        int sl = atomicAdd(&lcur[(v >> 17) & (BW - 1)], 1);
        entries[estart + sl] = v & 0x1FFFF;
    }
    if (b == 0 && t == 0) rstart[N] = E;
}

// ---------------------------------------------------------------------------
// Per-row u8 quantization: 32 lanes per node, lane holds 4 features.
// q = round(x * 127/rowmax) + 128 ; invs = rowmax/127
__global__ __launch_bounds__(256) void quant_kernel(const float* __restrict__ x,
                                                    uint* __restrict__ xq,
                                                    float* __restrict__ invs, int N) {
    int node = blockIdx.x * 8 + (threadIdx.x >> 5);
    if (node >= N) return;
    int l32 = threadIdx.x & 31;
    float4 v = ((const float4*)x)[node * 32 + l32];
    float m = fmaxf(fmaxf(fabsf(v.x), fabsf(v.y)), fmaxf(fabsf(v.z), fabsf(v.w)));
    #pragma unroll
    for (int mk = 1; mk < 32; mk <<= 1) m = fmaxf(m, __shfl_xor(m, mk));
    m = fmaxf(m, 1e-30f);
    float s = 127.0f / m;
    int q0 = min(255, max(0, (int)rintf(v.x * s) + 128));
    int q1 = min(255, max(0, (int)rintf(v.y * s) + 128));
    int q2 = min(255, max(0, (int)rintf(v.z * s) + 128));
    int q3 = min(255, max(0, (int)rintf(v.w * s) + 128));
    xq[node * 32 + l32] = (uint)q0 | ((uint)q1 << 8) | ((uint)q2 << 16) | ((uint)q3 << 24);
    if (l32 == 0) invs[node] = m / 127.0f;
}

// ---------------------------------------------------------------------------
// Pack W matrices into MFMA B-fragment layout (bf16), 3 planes:
//   mat 0: Wc_hi   mat 1: Ws_hi   mat 2: Ws_lo
__global__ __launch_bounds__(256) void wpack_kernel(const float* __restrict__ Wc,
                                                    const float* __restrict__ Ws,
                                                    short8* __restrict__ wp) {
    int t = blockIdx.x * 256 + threadIdx.x;   // 0..2047
    if (t >= 2048) return;
    int lane = t & 63;
    int nt = (t >> 6) & 7;
    int ks = t >> 9;
    int kbase = ks * 32 + (lane >> 4) * 8;
    int col = nt * 16 + (lane & 15);
    short8 whc, whs, wls;
    #pragma unroll
    for (int j = 0; j < 8; ++j) {
        float wc = Wc[(kbase + j) * H + col];
        float ws = Ws[(kbase + j) * H + col];
        unsigned short hc = f2bf(wc);
        unsigned short hs = f2bf(ws);
        whc[j] = (short)hc;
        whs[j] = (short)hs;
        wls[j] = (short)f2bf(ws - bf2f(hs));
    }
    int base = (ks * 8 + nt) * 64 + lane;
    wp[base] = whc;
    wp[2048 + base] = whs;
    wp[4096 + base] = wls;
}

// ---------------------------------------------------------------------------
// Gather aggregation on u8 x. One wave per node; half-wave (32 lanes x uint =
// 4 features each) per edge, 2 edges per iteration.
// z[f] = sum_e w_e*q_e[f] - 128*sum_e w_e + selfloop, w_e = ainv[src]*dinv[dst]
__global__ __launch_bounds__(256) void agg_kernel(const int* __restrict__ entries,
                                                  const int* __restrict__ rstart,
                                                  const float* __restrict__ dinv,
                                                  const float* __restrict__ ainv,
                                                  const float* __restrict__ invs,
                                                  const uint* __restrict__ xq,
                                                  unsigned short* __restrict__ z, int N) {
    int node = blockIdx.x * 4 + (threadIdx.x >> 6);
    if (node >= N) return;
    int lane = threadIdx.x & 63;
    int l32 = lane & 31;
    int half = lane >> 5;
    int start = rstart[node];
    int end = rstart[node + 1];
    float dd = dinv[node];
    float acc0 = 0.f, acc1 = 0.f, acc2 = 0.f, acc3 = 0.f, sumw = 0.f;

    for (int c = start; c < end; c += 64) {
        int rem = end - c;
        int src = 0;
        float w = 0.f;
        if (lane < rem) {
            src = entries[c + lane];
            w = ainv[src] * dd;
        }
        int cnt = rem < 64 ? rem : 64;
        int iters = (cnt + 1) >> 1;
        for (int t = 0; t < iters; ++t) {
            int idx = 2 * t + half;
            int ss = __shfl(src, idx);
            float wv = __shfl(w, idx);     // 0 when idx >= cnt (w was 0)
            uint q = xq[ss * 32 + l32];
            sumw += wv;
            acc0 += wv * (float)(q & 0xffu);
            acc1 += wv * (float)((q >> 8) & 0xffu);
            acc2 += wv * (float)((q >> 16) & 0xffu);
            acc3 += wv * (float)(q >> 24);
        }
    }

    // combine halves (lanes 0-31 end with totals)
    acc0 += __shfl_xor(acc0, 32);
    acc1 += __shfl_xor(acc1, 32);
    acc2 += __shfl_xor(acc2, 32);
    acc3 += __shfl_xor(acc3, 32);
    sumw += __shfl_xor(sumw, 32);

    if (half == 0) {
        // self-loop: weight 2*dd^2, decoded from own quantized row
        float wself = 2.f * dd * dd * invs[node];
        uint qs = xq[node * 32 + l32];
        sumw += wself;
        acc0 += wself * (float)(qs & 0xffu);
        acc1 += wself * (float)((qs >> 8) & 0xffu);
        acc2 += wself * (float)((qs >> 16) & 0xffu);
        acc3 += wself * (float)(qs >> 24);
        float off = 128.f * sumw;
        acc0 -= off; acc1 -= off; acc2 -= off; acc3 -= off;
        ushort4 o;
        o.x = f2bf(acc0); o.y = f2bf(acc1); o.z = f2bf(acc2); o.w = f2bf(acc3);
        ((ushort4*)z)[node * 32 + l32] = o;
    }
}

// ---------------------------------------------------------------------------
// MFMA GEMM: out = ELU( z@Wc + x@Ws + bc + bsk ), split-bf16 on the x path.
__global__ __launch_bounds__(256) void gemm_kernel(const unsigned short* __restrict__ zb,
                                                   const float* __restrict__ x,
                                                   const short8* __restrict__ wp,
                                                   const float* __restrict__ bc,
                                                   const float* __restrict__ bsk,
                                                   float* __restrict__ out, int N) {
    const int lane = threadIdx.x & 63;
    const int wave = threadIdx.x >> 6;
    const int m = lane & 15;
    const int quad = lane >> 4;
    const int row = blockIdx.x * 64 + wave * 16 + m;
    const bool rowok = row < N;

    f32x4 acc[8];
    #pragma unroll
    for (int i = 0; i < 8; ++i) acc[i] = (f32x4){0.f, 0.f, 0.f, 0.f};

    #pragma unroll
    for (int ks = 0; ks < 4; ++ks) {
        const int k0 = ks * 32 + quad * 8;
        short8 za = {0, 0, 0, 0, 0, 0, 0, 0};
        short8 xa_h = {0, 0, 0, 0, 0, 0, 0, 0};
        short8 xa_l = {0, 0, 0, 0, 0, 0, 0, 0};
        if (rowok) {
            za = ((const short8*)zb)[(row * H + k0) >> 3];
            float4 a = *(const float4*)&x[row * H + k0];
            float4 b = *(const float4*)&x[row * H + k0 + 4];
            float xv[8] = {a.x, a.y, a.z, a.w, b.x, b.y, b.z, b.w};
            #pragma unroll
            for (int j = 0; j < 8; ++j) {
                unsigned short h = f2bf(xv[j]);
                xa_h[j] = (short)h;
                xa_l[j] = (short)f2bf(xv[j] - bf2f(h));
            }
        }
        #pragma unroll
        for (int nt = 0; nt < 8; ++nt) {
            int base = (ks * 8 + nt) * 64 + lane;
            short8 bch = wp[base];
            short8 bsh = wp[2048 + base];
            short8 bsl = wp[4096 + base];
            acc[nt] = __builtin_amdgcn_mfma_f32_16x16x32_bf16(za, bch, acc[nt], 0, 0, 0);
            acc[nt] = __builtin_amdgcn_mfma_f32_16x16x32_bf16(xa_h, bsh, acc[nt], 0, 0, 0);
            acc[nt] = __builtin_amdgcn_mfma_f32_16x16x32_bf16(xa_l, bsh, acc[nt], 0, 0, 0);
            acc[nt] = __builtin_amdgcn_mfma_f32_16x16x32_bf16(xa_h, bsl, acc[nt], 0, 0, 0);
        }
    }

    const int orow_base = blockIdx.x * 64 + wave * 16 + quad * 4;
    #pragma unroll
    for (int nt = 0; nt < 8; ++nt) {
        int col = nt * 16 + m;
        float bias = bc[col] + bsk[col];
        #pragma unroll
        for (int r = 0; r < 4; ++r) {
            int orow = orow_base + r;
            if (orow < N) {
                float v = acc[nt][r] + bias;
                v = v > 0.f ? v : 0.1f * (__expf(v) - 1.f);
                out[orow * H + col] = v;
            }
        }
    }
}

// ---------------------------------------------------------------------------
extern "C" void kernel_launch(void* const* d_in, const int* in_sizes, int n_in,
                              void* d_out, int out_size, void* d_ws, size_t ws_size,
                              hipStream_t stream) {
    const float* x   = (const float*)d_in[0];
    const int*   ei  = (const int*)d_in[1];
    const float* Wc  = (const float*)d_in[2];
    const float* bc  = (const float*)d_in[3];
    const float* Wsk = (const float*)d_in[4];
    const float* bsk = (const float*)d_in[5];
    float* out = (float*)d_out;

    const int N = in_sizes[0] / H;       // 100000
    const int E = in_sizes[1] / 2;       // 1600000
    const int nbu = (N + BW - 1) / BW;   // 782 coarse buckets (<=1024)
    const int chunk = (E + NB - 1) / NB; // 6250 edges per partition block

    // workspace layout (byte offsets):
    //   0         cstart (nbu+1 ints)
    //   8K        btot (nbu ints)
    //   16K       wp (96KB)
    //   128K      rstart (N+1 ints, 400KB)
    //   576K      dinv (N f32, 400KB)
    //   1024K     invs (N f32, 400KB)
    //   1472K     ainv (N f32, 400KB)
    //   2M        counts (NB*nbu ints, ~800KB)
    //   3M        scanned (NB*nbu ints, ~800KB)
    //   4M        entries (E ints, 6.4MB)
    //   10.5M     tmp (E ints, 6.4MB) [dead after csr]; z (bf16 N*H, 25.6MB) overlays
    //   36.75M    xq (u8 N*H, 12.8MB)                  -> ends ~49.6M
    char* w = (char*)d_ws;
    int*            cstart  = (int*)w;
    int*            btot    = (int*)(w + 8192);
    short8*         wp      = (short8*)(w + 16384);
    int*            rstart  = (int*)(w + 131072);
    float*          dinv    = (float*)(w + 589824);
    float*          invs    = (float*)(w + 1048576);
    float*          ainv    = (float*)(w + 1507328);
    int*            counts  = (int*)(w + 2097152);
    int*            scanned = (int*)(w + 3145728);
    int*            entries = (int*)(w + 4194304);
    int*            tmp     = (int*)(w + 11010048);
    unsigned short* z       = (unsigned short*)(w + 11010048);
    uint*           xq      = (uint*)(w + 38535168);

    quant_kernel<<<(N + 7) / 8, 256, 0, stream>>>(x, xq, invs, N);

    p1_hist<<<NB, 256, 0, stream>>>(ei, counts, E, nbu, chunk);
    p2_scan<<<nbu, NB, 0, stream>>>(counts, scanned, btot, nbu);
    p3_scan<<<1, 1024, 0, stream>>>(btot, cstart, nbu, E);
    p5_scatter<<<NB, 256, 0, stream>>>(ei, cstart, scanned, tmp, E, nbu, chunk);
    csr_kernel<<<nbu, 256, 0, stream>>>(tmp, cstart, invs, entries, rstart, dinv, ainv, N, E);

    wpack_kernel<<<8, 256, 0, stream>>>(Wc, Wsk, wp);

    // z = sum(w * q[src]) - 128*sumw + selfloop (bf16)  [z overlays dead tmp]
    agg_kernel<<<(N + 3) / 4, 256, 0, stream>>>(entries, rstart, dinv, ainv, invs, xq, z, N);

    // out = ELU(z@Wc + x@Ws + biases)
    gemm_kernel<<<(N + 63) / 64, 256, 0, stream>>>(z, x, wp, bc, bsk, out, N);
}

// Round 7
// 272.927 us; speedup vs baseline: 2.4656x; 1.0418x over previous
//
#include <hip/hip_runtime.h>
#include <hip/hip_bf16.h>

#define H 128           // H_IN == H_OUT == 128
#define BW 128          // nodes per coarse bucket
#define BSH 7           // log2(BW)
#define NB 256          // partition blocks for counting sort

typedef __attribute__((ext_vector_type(8))) short short8;
typedef __attribute__((ext_vector_type(4))) float f32x4;

__device__ inline unsigned short f2bf(float f) {
    union { float f; unsigned int u; } v; v.f = f;
    unsigned int r = (v.u + 0x7fffu + ((v.u >> 16) & 1u)) >> 16;
    return (unsigned short)r;
}
__device__ inline float bf2f(unsigned short h) {
    union { unsigned int u; float f; } v; v.u = ((unsigned int)h) << 16;
    return v.f;
}

// ---------------------------------------------------------------------------
// P1: per-block LDS histogram of dst>>BSH over this block's edge chunk
__global__ __launch_bounds__(256) void p1_hist(const int* __restrict__ ei,
                                               int* __restrict__ counts,
                                               int E, int nbu, int chunk) {
    __shared__ int h[1024];
    for (int i = threadIdx.x; i < nbu; i += 256) h[i] = 0;
    __syncthreads();
    const int b = blockIdx.x;
    const int lo = b * chunk;
    const int hi = min(E, lo + chunk);
    for (int e = lo + threadIdx.x; e < hi; e += 256)
        atomicAdd(&h[ei[E + e] >> BSH], 1);
    __syncthreads();
    for (int i = threadIdx.x; i < nbu; i += 256) counts[b * nbu + i] = h[i];
}

// P2: per bucket, exclusive scan of its NB block-counts
__global__ __launch_bounds__(NB) void p2_scan(const int* __restrict__ counts,
                                              int* __restrict__ scanned,
                                              int* __restrict__ btot, int nbu) {
    __shared__ int s[NB];
    const int k = blockIdx.x, t = threadIdx.x;
    int v = counts[t * nbu + k];
    s[t] = v;
    __syncthreads();
    for (int off = 1; off < NB; off <<= 1) {
        int a = (t >= off) ? s[t - off] : 0;
        __syncthreads();
        s[t] += a;
        __syncthreads();
    }
    scanned[t * nbu + k] = s[t] - v;
    if (t == NB - 1) btot[k] = s[t];
}

// P3: exclusive scan of bucket totals -> cstart
__global__ __launch_bounds__(1024) void p3_scan(const int* __restrict__ btot,
                                                int* __restrict__ cstart,
                                                int nbu, int E) {
    __shared__ int s[1024];
    const int t = threadIdx.x;
    int v = (t < nbu) ? btot[t] : 0;
    s[t] = v;
    __syncthreads();
    for (int off = 1; off < 1024; off <<= 1) {
        int a = (t >= off) ? s[t - off] : 0;
        __syncthreads();
        s[t] += a;
        __syncthreads();
    }
    if (t < nbu) cstart[t] = s[t] - v;
    if (t == 0) cstart[nbu] = E;
}

// P5: scatter packed edges into exact slots (no global atomics)
__global__ __launch_bounds__(256) void p5_scatter(const int* __restrict__ ei,
                                                  const int* __restrict__ cstart,
                                                  const int* __restrict__ scanned,
                                                  int* __restrict__ tmp,
                                                  int E, int nbu, int chunk) {
    __shared__ int lbase[1024];
    const int b = blockIdx.x;
    for (int k = threadIdx.x; k < nbu; k += 256)
        lbase[k] = cstart[k] + scanned[b * nbu + k];
    __syncthreads();
    const int lo = b * chunk;
    const int hi = min(E, lo + chunk);
    for (int e = lo + threadIdx.x; e < hi; e += 256) {
        int s = ei[e], d = ei[E + e];
        int slot = atomicAdd(&lbase[d >> BSH], 1);
        tmp[slot] = ((d & (BW - 1)) << 17) | s;
    }
}

// Phase D: per bucket, local histogram + parallel scan -> rstart, dinv, ainv,
// entries (sorted per node within the bucket region)
__global__ __launch_bounds__(256) void csr_kernel(const int* __restrict__ tmp,
                                                  const int* __restrict__ cstart,
                                                  const float* __restrict__ invs,
                                                  int* __restrict__ entries,
                                                  int* __restrict__ rstart,
                                                  float* __restrict__ dinv,
                                                  float* __restrict__ ainv,
                                                  int N, int E) {
    __shared__ int ldeg[BW];
    __shared__ int lscan[BW];   // inclusive scan
    __shared__ int lcur[BW];
    const int b = blockIdx.x;
    const int nstart = b << BSH;
    const int estart = cstart[b];
    const int eend = cstart[b + 1];
    const int t = threadIdx.x;

    if (t < BW) ldeg[t] = 0;
    __syncthreads();
    for (int i = estart + t; i < eend; i += 256)
        atomicAdd(&ldeg[(tmp[i] >> 17) & (BW - 1)], 1);
    __syncthreads();
    if (t < BW) lscan[t] = ldeg[t];
    __syncthreads();
    #pragma unroll
    for (int off = 1; off < BW; off <<= 1) {
        int a = 0;
        if (t < BW && t >= off) a = lscan[t - off];
        __syncthreads();
        if (t < BW) lscan[t] += a;
        __syncthreads();
    }
    if (t < BW) {
        int excl = lscan[t] - ldeg[t];
        lcur[t] = excl;
        int n = nstart + t;
        if (n < N) {
            float dv = rsqrtf((float)ldeg[t] + 2.0f);
            rstart[n] = estart + excl;
            dinv[n] = dv;
            ainv[n] = dv * invs[n];
        }
    }
    __syncthreads();
    for (int i = estart + t; i < eend; i += 256) {
        int v = tmp[i];
        int sl = atomicAdd(&lcur[(v >> 17) & (BW - 1)], 1);
        entries[estart + sl] = v & 0x1FFFF;
    }
    if (b == 0 && t == 0) rstart[N] = E;
}

// ---------------------------------------------------------------------------
// Per-row u8 quantization: 32 lanes per node, lane holds 4 features.
// q = round(x * 127/rowmax) + 128 ; invs = rowmax/127
__global__ __launch_bounds__(256) void quant_kernel(const float* __restrict__ x,
                                                    uint* __restrict__ xq,
                                                    float* __restrict__ invs, int N) {
    int node = blockIdx.x * 8 + (threadIdx.x >> 5);
    if (node >= N) return;
    int l32 = threadIdx.x & 31;
    float4 v = ((const float4*)x)[node * 32 + l32];
    float m = fmaxf(fmaxf(fabsf(v.x), fabsf(v.y)), fmaxf(fabsf(v.z), fabsf(v.w)));
    #pragma unroll
    for (int mk = 1; mk < 32; mk <<= 1) m = fmaxf(m, __shfl_xor(m, mk));
    m = fmaxf(m, 1e-30f);
    float s = 127.0f / m;
    int q0 = min(255, max(0, (int)rintf(v.x * s) + 128));
    int q1 = min(255, max(0, (int)rintf(v.y * s) + 128));
    int q2 = min(255, max(0, (int)rintf(v.z * s) + 128));
    int q3 = min(255, max(0, (int)rintf(v.w * s) + 128));
    xq[node * 32 + l32] = (uint)q0 | ((uint)q1 << 8) | ((uint)q2 << 16) | ((uint)q3 << 24);
    if (l32 == 0) invs[node] = m / 127.0f;
}

// ---------------------------------------------------------------------------
// Pack W matrices into MFMA B-fragment layout (bf16), 3 planes:
//   mat 0: Wc_hi   mat 1: Ws_hi   mat 2: Ws_lo
__global__ __launch_bounds__(256) void wpack_kernel(const float* __restrict__ Wc,
                                                    const float* __restrict__ Ws,
                                                    short8* __restrict__ wp) {
    int t = blockIdx.x * 256 + threadIdx.x;   // 0..2047
    if (t >= 2048) return;
    int lane = t & 63;
    int nt = (t >> 6) & 7;
    int ks = t >> 9;
    int kbase = ks * 32 + (lane >> 4) * 8;
    int col = nt * 16 + (lane & 15);
    short8 whc, whs, wls;
    #pragma unroll
    for (int j = 0; j < 8; ++j) {
        float wc = Wc[(kbase + j) * H + col];
        float ws = Ws[(kbase + j) * H + col];
        unsigned short hc = f2bf(wc);
        unsigned short hs = f2bf(ws);
        whc[j] = (short)hc;
        whs[j] = (short)hs;
        wls[j] = (short)f2bf(ws - bf2f(hs));
    }
    int base = (ks * 8 + nt) * 64 + lane;
    wp[base] = whc;
    wp[2048 + base] = whs;
    wp[4096 + base] = wls;
}

// ---------------------------------------------------------------------------
// Gather aggregation on u8 x. One wave per node; QUARTER-wave (16 lanes x
// uint2 = 8 features each) per edge -> 4 edges per iteration, one dwordx2
// load each. #pragma unroll 4 keeps 4 loads outstanding.
// z[f] = sum_e w_e*q_e[f] - 128*sum_e w_e + selfloop, w_e = ainv[src]*dinv[dst]
__global__ __launch_bounds__(256) void agg_kernel(const int* __restrict__ entries,
                                                  const int* __restrict__ rstart,
                                                  const float* __restrict__ dinv,
                                                  const float* __restrict__ ainv,
                                                  const float* __restrict__ invs,
                                                  const uint* __restrict__ xq,
                                                  unsigned short* __restrict__ z, int N) {
    int node = blockIdx.x * 4 + (threadIdx.x >> 6);
    if (node >= N) return;
    int lane = threadIdx.x & 63;
    int l16 = lane & 15;
    int q4 = lane >> 4;
    int start = rstart[node];
    int end = rstart[node + 1];
    float dd = dinv[node];
    const uint2* x2 = (const uint2*)xq;   // 8 features per element
    float acc[8] = {0.f, 0.f, 0.f, 0.f, 0.f, 0.f, 0.f, 0.f};
    float sumw = 0.f;

    for (int c = start; c < end; c += 64) {
        int rem = end - c;
        int src = 0;
        float w = 0.f;
        if (lane < rem) {
            src = entries[c + lane];
            w = ainv[src] * dd;
        }
        int cnt = rem < 64 ? rem : 64;
        int iters = (cnt + 3) >> 2;
        #pragma unroll 4
        for (int t = 0; t < iters; ++t) {
            int idx = 4 * t + q4;
            int ss = __shfl(src, idx);
            float wv = __shfl(w, idx);     // 0 when idx >= cnt
            uint2 q = x2[ss * 16 + l16];
            sumw += wv;
            acc[0] += wv * (float)(q.x & 0xffu);
            acc[1] += wv * (float)((q.x >> 8) & 0xffu);
            acc[2] += wv * (float)((q.x >> 16) & 0xffu);
            acc[3] += wv * (float)(q.x >> 24);
            acc[4] += wv * (float)(q.y & 0xffu);
            acc[5] += wv * (float)((q.y >> 8) & 0xffu);
            acc[6] += wv * (float)((q.y >> 16) & 0xffu);
            acc[7] += wv * (float)(q.y >> 24);
        }
    }

    // combine quarters (lanes 0-15 end with totals)
    #pragma unroll
    for (int j = 0; j < 8; ++j) {
        acc[j] += __shfl_xor(acc[j], 16);
        acc[j] += __shfl_xor(acc[j], 32);
    }
    sumw += __shfl_xor(sumw, 16);
    sumw += __shfl_xor(sumw, 32);

    if (q4 == 0) {
        // self-loop: weight 2*dd^2, decoded from own quantized row
        float wself = 2.f * dd * dd * invs[node];
        uint2 qs = x2[node * 16 + l16];
        sumw += wself;
        acc[0] += wself * (float)(qs.x & 0xffu);
        acc[1] += wself * (float)((qs.x >> 8) & 0xffu);
        acc[2] += wself * (float)((qs.x >> 16) & 0xffu);
        acc[3] += wself * (float)(qs.x >> 24);
        acc[4] += wself * (float)(qs.y & 0xffu);
        acc[5] += wself * (float)((qs.y >> 8) & 0xffu);
        acc[6] += wself * (float)((qs.y >> 16) & 0xffu);
        acc[7] += wself * (float)(qs.y >> 24);
        float off = 128.f * sumw;
        uint4 o;
        o.x = (uint)f2bf(acc[0] - off) | ((uint)f2bf(acc[1] - off) << 16);
        o.y = (uint)f2bf(acc[2] - off) | ((uint)f2bf(acc[3] - off) << 16);
        o.z = (uint)f2bf(acc[4] - off) | ((uint)f2bf(acc[5] - off) << 16);
        o.w = (uint)f2bf(acc[6] - off) | ((uint)f2bf(acc[7] - off) << 16);
        ((uint4*)z)[node * 16 + l16] = o;
    }
}

// ---------------------------------------------------------------------------
// MFMA GEMM: out = ELU( z@Wc + x@Ws + bc + bsk ), split-bf16 on the x path.
__global__ __launch_bounds__(256) void gemm_kernel(const unsigned short* __restrict__ zb,
                                                   const float* __restrict__ x,
                                                   const short8* __restrict__ wp,
                                                   const float* __restrict__ bc,
                                                   const float* __restrict__ bsk,
                                                   float* __restrict__ out, int N) {
    const int lane = threadIdx.x & 63;
    const int wave = threadIdx.x >> 6;
    const int m = lane & 15;
    const int quad = lane >> 4;
    const int row = blockIdx.x * 64 + wave * 16 + m;
    const bool rowok = row < N;

    f32x4 acc[8];
    #pragma unroll
    for (int i = 0; i < 8; ++i) acc[i] = (f32x4){0.f, 0.f, 0.f, 0.f};

    #pragma unroll
    for (int ks = 0; ks < 4; ++ks) {
        const int k0 = ks * 32 + quad * 8;
        short8 za = {0, 0, 0, 0, 0, 0, 0, 0};
        short8 xa_h = {0, 0, 0, 0, 0, 0, 0, 0};
        short8 xa_l = {0, 0, 0, 0, 0, 0, 0, 0};
        if (rowok) {
            za = ((const short8*)zb)[(row * H + k0) >> 3];
            float4 a = *(const float4*)&x[row * H + k0];
            float4 b = *(const float4*)&x[row * H + k0 + 4];
            float xv[8] = {a.x, a.y, a.z, a.w, b.x, b.y, b.z, b.w};
            #pragma unroll
            for (int j = 0; j < 8; ++j) {
                unsigned short h = f2bf(xv[j]);
                xa_h[j] = (short)h;
                xa_l[j] = (short)f2bf(xv[j] - bf2f(h));
            }
        }
        #pragma unroll
        for (int nt = 0; nt < 8; ++nt) {
            int base = (ks * 8 + nt) * 64 + lane;
            short8 bch = wp[base];
            short8 bsh = wp[2048 + base];
            short8 bsl = wp[4096 + base];
            acc[nt] = __builtin_amdgcn_mfma_f32_16x16x32_bf16(za, bch, acc[nt], 0, 0, 0);
            acc[nt] = __builtin_amdgcn_mfma_f32_16x16x32_bf16(xa_h, bsh, acc[nt], 0, 0, 0);
            acc[nt] = __builtin_amdgcn_mfma_f32_16x16x32_bf16(xa_l, bsh, acc[nt], 0, 0, 0);
            acc[nt] = __builtin_amdgcn_mfma_f32_16x16x32_bf16(xa_h, bsl, acc[nt], 0, 0, 0);
        }
    }

    const int orow_base = blockIdx.x * 64 + wave * 16 + quad * 4;
    #pragma unroll
    for (int nt = 0; nt < 8; ++nt) {
        int col = nt * 16 + m;
        float bias = bc[col] + bsk[col];
        #pragma unroll
        for (int r = 0; r < 4; ++r) {
            int orow = orow_base + r;
            if (orow < N) {
                float v = acc[nt][r] + bias;
                v = v > 0.f ? v : 0.1f * (__expf(v) - 1.f);
                out[orow * H + col] = v;
            }
        }
    }
}

// ---------------------------------------------------------------------------
extern "C" void kernel_launch(void* const* d_in, const int* in_sizes, int n_in,
                              void* d_out, int out_size, void* d_ws, size_t ws_size,
                              hipStream_t stream) {
    const float* x   = (const float*)d_in[0];
    const int*   ei  = (const int*)d_in[1];
    const float* Wc  = (const float*)d_in[2];
    const float* bc  = (const float*)d_in[3];
    const float* Wsk = (const float*)d_in[4];
    const float* bsk = (const float*)d_in[5];
    float* out = (float*)d_out;

    const int N = in_sizes[0] / H;       // 100000
    const int E = in_sizes[1] / 2;       // 1600000
    const int nbu = (N + BW - 1) / BW;   // 782 coarse buckets (<=1024)
    const int chunk = (E + NB - 1) / NB; // 6250 edges per partition block

    // workspace layout (byte offsets):
    //   0         cstart (nbu+1 ints)
    //   8K        btot (nbu ints)
    //   16K       wp (96KB)
    //   128K      rstart (N+1 ints, 400KB)
    //   576K      dinv (N f32, 400KB)
    //   1024K     invs (N f32, 400KB)
    //   1472K     ainv (N f32, 400KB)
    //   2M        counts (NB*nbu ints, ~800KB)
    //   3M        scanned (NB*nbu ints, ~800KB)
    //   4M        entries (E ints, 6.4MB)
    //   10.5M     tmp (E ints, 6.4MB) [dead after csr]; z (bf16 N*H, 25.6MB) overlays
    //   36.75M    xq (u8 N*H, 12.8MB)                  -> ends ~49.6M
    char* w = (char*)d_ws;
    int*            cstart  = (int*)w;
    int*            btot    = (int*)(w + 8192);
    short8*         wp      = (short8*)(w + 16384);
    int*            rstart  = (int*)(w + 131072);
    float*          dinv    = (float*)(w + 589824);
    float*          invs    = (float*)(w + 1048576);
    float*          ainv    = (float*)(w + 1507328);
    int*            counts  = (int*)(w + 2097152);
    int*            scanned = (int*)(w + 3145728);
    int*            entries = (int*)(w + 4194304);
    int*            tmp     = (int*)(w + 11010048);
    unsigned short* z       = (unsigned short*)(w + 11010048);
    uint*           xq      = (uint*)(w + 38535168);

    quant_kernel<<<(N + 7) / 8, 256, 0, stream>>>(x, xq, invs, N);

    p1_hist<<<NB, 256, 0, stream>>>(ei, counts, E, nbu, chunk);
    p2_scan<<<nbu, NB, 0, stream>>>(counts, scanned, btot, nbu);
    p3_scan<<<1, 1024, 0, stream>>>(btot, cstart, nbu, E);
    p5_scatter<<<NB, 256, 0, stream>>>(ei, cstart, scanned, tmp, E, nbu, chunk);
    csr_kernel<<<nbu, 256, 0, stream>>>(tmp, cstart, invs, entries, rstart, dinv, ainv, N, E);

    wpack_kernel<<<8, 256, 0, stream>>>(Wc, Wsk, wp);

    // z = sum(w * q[src]) - 128*sumw + selfloop (bf16)  [z overlays dead tmp]
    agg_kernel<<<(N + 3) / 4, 256, 0, stream>>>(entries, rstart, dinv, ainv, invs, xq, z, N);

    // out = ELU(z@Wc + x@Ws + biases)
    gemm_kernel<<<(N + 63) / 64, 256, 0, stream>>>(z, x, wp, bc, bsk, out, N);
}